// Round 3
// baseline (800.594 us; speedup 1.0000x reference)
//
#include <hip/hip_runtime.h>
#include <cstdint>

typedef unsigned short u16;
typedef unsigned int   u32;
typedef unsigned long long u64;

#define G_ROWS 20000
#define G_PAD  20096      // 157 * 128
#define T_DIM  1536
#define D_DIM  512
#define B_DIM  256
#define TOPK   32
#define NCAND  40
#define SIM_SCALE 0.04419417382415922f   // 1/sqrt(512), screening only
#define SQRT_D    22.62741699796952f     // f32(math.sqrt(512)) — np divides by this

typedef __bf16 bf16x8 __attribute__((ext_vector_type(8)));
typedef float  f32x4  __attribute__((ext_vector_type(4)));

__device__ __forceinline__ u16 f2bf(float f) {
  u32 u = __float_as_uint(f);
  u += 0x7fffu + ((u >> 16) & 1u);   // RNE
  return (u16)(u >> 16);
}
__device__ __forceinline__ float bf2f(u16 h) {
  return __uint_as_float(((u32)h) << 16);
}

// ---------------- split-conversion: f32 -> (bf16 hi, bf16 lo) ----------------
__global__ __launch_bounds__(256) void conv_split(const float* __restrict__ src,
                                                  u16* __restrict__ hi, u16* __restrict__ lo,
                                                  int valid_rows)
{
  size_t i = ((size_t)blockIdx.x * 256 + threadIdx.x) * 4;
  int row = (int)(i >> 9);
  float4 a = make_float4(0.f, 0.f, 0.f, 0.f);
  if (row < valid_rows) a = *(const float4*)(src + i);
  float v[4] = {a.x, a.y, a.z, a.w};
  u16 h[4], l[4];
#pragma unroll
  for (int c = 0; c < 4; ++c) {
    h[c] = f2bf(v[c]);
    l[c] = f2bf(v[c] - bf2f(h[c]));
  }
  *(uint2*)(hi + i) = make_uint2((u32)h[0] | ((u32)h[1] << 16), (u32)h[2] | ((u32)h[3] << 16));
  *(uint2*)(lo + i) = make_uint2((u32)l[0] | ((u32)l[1] << 16), (u32)l[2] | ((u32)l[3] << 16));
}

// ---------------- tf_expr [B,T] -> tfT [T,B] ----------------
__global__ __launch_bounds__(256) void transpose_tf(const float* __restrict__ in, float* __restrict__ out)
{
  __shared__ float tile[32][33];
  int x = threadIdx.x, y = threadIdx.y;
  int bt = blockIdx.x * 32;
  int bb = blockIdx.y * 32;
#pragma unroll
  for (int i = 0; i < 32; i += 8) tile[y + i][x] = in[(size_t)(bb + y + i) * T_DIM + bt + x];
  __syncthreads();
#pragma unroll
  for (int i = 0; i < 32; i += 8) out[(size_t)(bt + y + i) * B_DIM + bb + x] = tile[x][y + i];
}

// ---------------- async global -> LDS, 16B/lane ----------------
__device__ __forceinline__ void gl16(const u16* g, u16* l) {
  __builtin_amdgcn_global_load_lds((__attribute__((address_space(1))) void*)(void*)g,
                                   (__attribute__((address_space(3))) void*)l, 16, 0, 0);
}

// ---------------- screening GEMM: C ~= (Ah+Al)(Bh+Bl)^T via 3 bf16 MFMA terms ----------------
__global__ __launch_bounds__(256) void gemm_split(const u16* __restrict__ Ah, const u16* __restrict__ Al,
                                                  const u16* __restrict__ Bh, const u16* __restrict__ Bl,
                                                  float* __restrict__ Sim)
{
  __shared__ u16 sm[16384];
  const int tid  = threadIdx.x;
  const int lane = tid & 63;
  const int wv   = tid >> 6;
  const int m0 = blockIdx.y * 128;
  const int n0 = blockIdx.x * 128;

  f32x4 zero4 = {0.f, 0.f, 0.f, 0.f};
  f32x4 acc[4][4];
#pragma unroll
  for (int i = 0; i < 4; ++i)
#pragma unroll
    for (int j = 0; j < 4; ++j) acc[i][j] = zero4;

  const int r0 = (wv << 4) + (lane >> 2);
  const int c0 = (lane & 3) << 3;
  const size_t aoff = (size_t)(m0 + r0) * 512 + c0;
  const size_t boff = (size_t)(n0 + r0) * 512 + c0;
  u16* lw = sm + (wv << 9);

  const int arow = ((wv >> 1) << 6) + (lane & 15);
  const int brow = ((wv & 1) << 6) + (lane & 15);
  const int kf   = (lane >> 4) << 3;

  for (int kt = 0; kt < 16; ++kt) {
    const int k0 = kt << 5;
    __syncthreads();
    gl16(Ah + aoff + k0,            lw);
    gl16(Ah + aoff + k0 + 64 * 512, lw + 2048);
    gl16(Al + aoff + k0,            lw + 4096);
    gl16(Al + aoff + k0 + 64 * 512, lw + 6144);
    gl16(Bh + boff + k0,            lw + 8192);
    gl16(Bh + boff + k0 + 64 * 512, lw + 10240);
    gl16(Bl + boff + k0,            lw + 12288);
    gl16(Bl + boff + k0 + 64 * 512, lw + 14336);
    __syncthreads();

    bf16x8 aH[4], aL[4], bH[4], bL[4];
#pragma unroll
    for (int mi = 0; mi < 4; ++mi) {
      aH[mi] = *(const bf16x8*)(sm +        (arow + mi * 16) * 32 + kf);
      aL[mi] = *(const bf16x8*)(sm + 4096 + (arow + mi * 16) * 32 + kf);
    }
#pragma unroll
    for (int ni = 0; ni < 4; ++ni) {
      bH[ni] = *(const bf16x8*)(sm + 8192  + (brow + ni * 16) * 32 + kf);
      bL[ni] = *(const bf16x8*)(sm + 12288 + (brow + ni * 16) * 32 + kf);
    }
#pragma unroll
    for (int mi = 0; mi < 4; ++mi)
#pragma unroll
      for (int ni = 0; ni < 4; ++ni) {
        acc[mi][ni] = __builtin_amdgcn_mfma_f32_16x16x32_bf16(aH[mi], bH[ni], acc[mi][ni], 0, 0, 0);
        acc[mi][ni] = __builtin_amdgcn_mfma_f32_16x16x32_bf16(aH[mi], bL[ni], acc[mi][ni], 0, 0, 0);
        acc[mi][ni] = __builtin_amdgcn_mfma_f32_16x16x32_bf16(aL[mi], bH[ni], acc[mi][ni], 0, 0, 0);
      }
  }

  const int erow0 = m0 + ((wv >> 1) << 6) + ((lane >> 4) << 2);
  const int ecol0 = n0 + ((wv & 1) << 6) + (lane & 15);
#pragma unroll
  for (int mi = 0; mi < 4; ++mi)
#pragma unroll
    for (int r = 0; r < 4; ++r) {
      int row = erow0 + mi * 16 + r;
      if (row < G_ROWS) {
#pragma unroll
        for (int ni = 0; ni < 4; ++ni)
          Sim[(size_t)row * T_DIM + ecol0 + ni * 16] = acc[mi][ni][r] * SIM_SCALE;
      }
    }
}

// ---------------- per-row (1 wave/row): screen top-40, np-replica f32 re-sim,
// rank by replica, top-32 select + renormalized sparse write ----------------
__global__ __launch_bounds__(256) void topk_kernel(float* __restrict__ Sim, const int* __restrict__ mask,
                                                   const float* __restrict__ tg_dec,
                                                   const float* __restrict__ tf_base,
                                                   int* __restrict__ tIdx, float* __restrict__ tW)
{
  __shared__ float srow[4][T_DIM];   // 24 KB
  const int lane = threadIdx.x & 63;
  const int wv   = threadIdx.x >> 6;
  const int g    = blockIdx.x * 4 + wv;
  float* row = Sim + (size_t)g * T_DIM;
  const int* mrow = mask + (size_t)g * T_DIM;

  // --- screened masked softmax stats (m, Z cancel in final ratio; only 1e-8*Z term uses them) ---
  float p[24];
  float m = -INFINITY;
#pragma unroll
  for (int j = 0; j < 24; ++j) {
    float v = row[j * 64 + lane];
    int mk = mrow[j * 64 + lane];
    v = (mk != 0) ? v : -INFINITY;
    p[j] = v;
    m = fmaxf(m, v);
  }
#pragma unroll
  for (int off = 32; off > 0; off >>= 1) m = fmaxf(m, __shfl_xor(m, off, 64));

  float Z = 0.f;
#pragma unroll
  for (int j = 0; j < 24; ++j) {
    float e = (p[j] == -INFINITY) ? 0.f : __expf(p[j] - m);
    p[j] = e;
    Z += e;
  }
#pragma unroll
  for (int off = 32; off > 0; off >>= 1) Z += __shfl_xor(Z, off, 64);

  // --- extract NCAND screened candidates (lane c holds candidate c) ---
  u32 sel = 0;
  int candIdx = 0;
  for (int it = 0; it < NCAND; ++it) {
    float bv = -1.f; int bj = 0;
#pragma unroll
    for (int j = 0; j < 24; ++j) {
      float v = ((sel >> j) & 1u) ? -1.f : p[j];
      if (v > bv) { bv = v; bj = j; }
    }
    bv = fmaxf(bv, 0.f);
    int bt = bj * 64 + lane;
    u64 key = ((u64)__float_as_uint(bv) << 32) | (u32)(~(u32)bt);
#pragma unroll
    for (int off = 32; off > 0; off >>= 1) {
      u64 o = __shfl_xor(key, off, 64);
      if (o > key) key = o;
    }
    int wt = (int)(~(u32)(key & 0xFFFFFFFFull));
    if (lane == (wt & 63)) sel |= (1u << (wt >> 6));
    if (lane == it) candIdx = wt;
  }

  // --- np-replica f32 re-sim: OpenBLAS sgemm = sequential-K FMA chain per output,
  //     kc-panel split 384|128 (ZEN SGEMM_DEFAULT_Q=384), then f32 division by f32(sqrt(512)).
  //     Strict FP (no fast-math) preserves the exact chain order. ---
  const float* arow_g = tg_dec + (size_t)g * D_DIM;
  const float* brow = tf_base + (size_t)((lane < NCAND) ? candIdx : 0) * D_DIM;
  float s1 = 0.f, s2 = 0.f;
#pragma unroll 8
  for (int k = 0; k < 384; k += 4) {
    float4 av = *(const float4*)(arow_g + k);
    float4 bv = *(const float4*)(brow + k);
    s1 = fmaf(av.x, bv.x, s1);
    s1 = fmaf(av.y, bv.y, s1);
    s1 = fmaf(av.z, bv.z, s1);
    s1 = fmaf(av.w, bv.w, s1);
  }
#pragma unroll 8
  for (int k = 384; k < 512; k += 4) {
    float4 av = *(const float4*)(arow_g + k);
    float4 bv = *(const float4*)(brow + k);
    s2 = fmaf(av.x, bv.x, s2);
    s2 = fmaf(av.y, bv.y, s2);
    s2 = fmaf(av.z, bv.z, s2);
    s2 = fmaf(av.w, bv.w, s2);
  }
  float myS = (s1 + s2) / SQRT_D;          // matches np's `matmul / math.sqrt(512)` in f32
  if (lane >= NCAND) myS = -INFINITY;

  // --- rank by (replica sim desc, idx asc) — np stable argsort tie rule ---
  int rank = 0;
  for (int c = 0; c < NCAND; ++c) {
    float rv = __shfl(myS, c, 64);
    int ridx = __shfl(candIdx, c, 64);
    bool gt = (rv > myS) || (rv == myS && ridx < candIdx);
    rank += gt ? 1 : 0;
  }
  const bool selme = (lane < NCAND) && (rank < TOPK);

  // --- weights from replica sims (shared m cancels; Z only in the 1e-8 term) ---
  float e_c = selme ? __expf(myS - m) : 0.f;
  float E32 = e_c;
#pragma unroll
  for (int off = 32; off > 0; off >>= 1) E32 += __shfl_xor(E32, off, 64);
  float den = E32 + 1e-8f * Z;
  float rden = (den > 0.f) ? (1.f / den) : 0.f;
  float w = e_c * rden;

  // --- write sparse row via LDS (zero -> scatter -> dense writeback) ---
  float* sr = srow[wv];
#pragma unroll
  for (int j = 0; j < 24; ++j) sr[j * 64 + lane] = 0.f;
  __syncthreads();
  if (selme) sr[candIdx] = w;
  __syncthreads();
#pragma unroll
  for (int j = 0; j < 24; ++j) row[j * 64 + lane] = sr[j * 64 + lane];

  if (selme) {
    tIdx[(size_t)g * TOPK + rank] = candIdx;
    tW[(size_t)g * TOPK + rank]   = w;
  }
}

// ---------------- out0[b,g] = scale * sum_k w[g,k] * tfT[idx[g,k], b] ----------------
__global__ __launch_bounds__(256) void combine_kernel(const float* __restrict__ tfT, const int* __restrict__ tIdx,
                                                      const float* __restrict__ tW, const float* __restrict__ scalep,
                                                      float* __restrict__ out0)
{
  __shared__ int   sIdx[16 * 32];
  __shared__ float sW[16 * 32];
  const int tid = threadIdx.x;
  const int g0 = blockIdx.x * 16;
  for (int i = tid; i < 512; i += 256) {
    sIdx[i] = tIdx[(size_t)g0 * 32 + i];
    sW[i]   = tW[(size_t)g0 * 32 + i];
  }
  __syncthreads();
  const float scale = scalep[0];
  float acc[16];
#pragma unroll
  for (int gi = 0; gi < 16; ++gi) acc[gi] = 0.f;
#pragma unroll 4
  for (int gi = 0; gi < 16; ++gi) {
    float a = 0.f;
#pragma unroll
    for (int k = 0; k < 32; ++k) {
      float w = sW[gi * 32 + k];
      int t   = sIdx[gi * 32 + k];
      a += w * tfT[(size_t)t * B_DIM + tid];
    }
    acc[gi] = a;
  }
  float* dst = out0 + (size_t)tid * G_ROWS + g0;
#pragma unroll
  for (int q = 0; q < 4; ++q) {
    float4 o = make_float4(scale * acc[4*q], scale * acc[4*q+1], scale * acc[4*q+2], scale * acc[4*q+3]);
    *(float4*)(dst + 4 * q) = o;
  }
}

extern "C" void kernel_launch(void* const* d_in, const int* in_sizes, int n_in,
                              void* d_out, int out_size, void* d_ws, size_t ws_size,
                              hipStream_t stream)
{
  const float* tg_dec     = (const float*)d_in[0];
  const float* tf_base    = (const float*)d_in[1];
  const float* tf_expr    = (const float*)d_in[2];
  const int*   motif_mask = (const int*)d_in[3];
  const float* scale      = (const float*)d_in[4];

  float* out0 = (float*)d_out;                           // [B, G]
  float* attn = out0 + (size_t)B_DIM * G_ROWS;           // [G, T] — also Sim scratch

  char* ws = (char*)d_ws;
  u16*   Ah  = (u16*)(ws);                               // G_PAD*512 bf16
  u16*   Al  = (u16*)(ws + 20578304);
  u16*   Bh  = (u16*)(ws + 41156608);                    // 1536*512 bf16
  u16*   Bl  = (u16*)(ws + 42729472);
  float* tfT = (float*)(ws + 44302336);                  // [T, B] f32
  int*   tIdx = (int*)(ws + 45875200);                   // [G, 32]
  float* tW   = (float*)(ws + 48435200);                 // [G, 32]

  conv_split<<<10048, 256, 0, stream>>>(tg_dec, Ah, Al, G_ROWS);
  conv_split<<<768,   256, 0, stream>>>(tf_base, Bh, Bl, T_DIM);
  transpose_tf<<<dim3(48, 8), dim3(32, 8), 0, stream>>>(tf_expr, tfT);
  gemm_split<<<dim3(12, 157), 256, 0, stream>>>(Ah, Al, Bh, Bl, attn);
  topk_kernel<<<5000, 256, 0, stream>>>(attn, motif_mask, tg_dec, tf_base, tIdx, tW);
  combine_kernel<<<1250, 256, 0, stream>>>(tfT, tIdx, tW, scale, out0);
}

// Round 4
// 603.942 us; speedup vs baseline: 1.3256x; 1.3256x over previous
//
#include <hip/hip_runtime.h>
#include <cstdint>

typedef unsigned short u16;
typedef unsigned int   u32;
typedef unsigned long long u64;

#define G_ROWS 20000
#define G_PAD  20096      // 157 * 128
#define T_DIM  1536
#define D_DIM  512
#define B_DIM  256
#define TOPK   32
#define SIM_SCALE 0.04419417382415922f   // 1/sqrt(512), screening only
#define SQRT_D    22.62741699796952f     // f32(math.sqrt(512)) — np divides by this
#define BOUND_EPS 2.0e-4f                // screen-vs-np noise is ~5e-6; 40x margin

typedef __bf16 bf16x8 __attribute__((ext_vector_type(8)));
typedef float  f32x4  __attribute__((ext_vector_type(4)));

__device__ __forceinline__ u16 f2bf(float f) {
  u32 u = __float_as_uint(f);
  u += 0x7fffu + ((u >> 16) & 1u);   // RNE
  return (u16)(u >> 16);
}
__device__ __forceinline__ float bf2f(u16 h) {
  return __uint_as_float(((u32)h) << 16);
}

// ---------------- split-conversion: f32 -> (bf16 hi, bf16 lo) ----------------
__global__ __launch_bounds__(256) void conv_split(const float* __restrict__ src,
                                                  u16* __restrict__ hi, u16* __restrict__ lo,
                                                  int valid_rows)
{
  size_t i = ((size_t)blockIdx.x * 256 + threadIdx.x) * 4;
  int row = (int)(i >> 9);
  float4 a = make_float4(0.f, 0.f, 0.f, 0.f);
  if (row < valid_rows) a = *(const float4*)(src + i);
  float v[4] = {a.x, a.y, a.z, a.w};
  u16 h[4], l[4];
#pragma unroll
  for (int c = 0; c < 4; ++c) {
    h[c] = f2bf(v[c]);
    l[c] = f2bf(v[c] - bf2f(h[c]));
  }
  *(uint2*)(hi + i) = make_uint2((u32)h[0] | ((u32)h[1] << 16), (u32)h[2] | ((u32)h[3] << 16));
  *(uint2*)(lo + i) = make_uint2((u32)l[0] | ((u32)l[1] << 16), (u32)l[2] | ((u32)l[3] << 16));
}

// ---------------- tf_expr [B,T] -> tfT [T,B] ----------------
__global__ __launch_bounds__(256) void transpose_tf(const float* __restrict__ in, float* __restrict__ out)
{
  __shared__ float tile[32][33];
  int x = threadIdx.x, y = threadIdx.y;
  int bt = blockIdx.x * 32;
  int bb = blockIdx.y * 32;
#pragma unroll
  for (int i = 0; i < 32; i += 8) tile[y + i][x] = in[(size_t)(bb + y + i) * T_DIM + bt + x];
  __syncthreads();
#pragma unroll
  for (int i = 0; i < 32; i += 8) out[(size_t)(bt + y + i) * B_DIM + bb + x] = tile[x][y + i];
}

// ---------------- async global -> LDS, 16B/lane ----------------
__device__ __forceinline__ void gl16(const u16* g, u16* l) {
  __builtin_amdgcn_global_load_lds((__attribute__((address_space(1))) void*)(void*)g,
                                   (__attribute__((address_space(3))) void*)l, 16, 0, 0);
}

// ---------------- screening GEMM: C ~= (Ah+Al)(Bh+Bl)^T via 3 bf16 MFMA terms ----------------
__global__ __launch_bounds__(256) void gemm_split(const u16* __restrict__ Ah, const u16* __restrict__ Al,
                                                  const u16* __restrict__ Bh, const u16* __restrict__ Bl,
                                                  float* __restrict__ Sim)
{
  __shared__ u16 sm[16384];
  const int tid  = threadIdx.x;
  const int lane = tid & 63;
  const int wv   = tid >> 6;
  const int m0 = blockIdx.y * 128;
  const int n0 = blockIdx.x * 128;

  f32x4 zero4 = {0.f, 0.f, 0.f, 0.f};
  f32x4 acc[4][4];
#pragma unroll
  for (int i = 0; i < 4; ++i)
#pragma unroll
    for (int j = 0; j < 4; ++j) acc[i][j] = zero4;

  const int r0 = (wv << 4) + (lane >> 2);
  const int c0 = (lane & 3) << 3;
  const size_t aoff = (size_t)(m0 + r0) * 512 + c0;
  const size_t boff = (size_t)(n0 + r0) * 512 + c0;
  u16* lw = sm + (wv << 9);

  const int arow = ((wv >> 1) << 6) + (lane & 15);
  const int brow = ((wv & 1) << 6) + (lane & 15);
  const int kf   = (lane >> 4) << 3;

  for (int kt = 0; kt < 16; ++kt) {
    const int k0 = kt << 5;
    __syncthreads();
    gl16(Ah + aoff + k0,            lw);
    gl16(Ah + aoff + k0 + 64 * 512, lw + 2048);
    gl16(Al + aoff + k0,            lw + 4096);
    gl16(Al + aoff + k0 + 64 * 512, lw + 6144);
    gl16(Bh + boff + k0,            lw + 8192);
    gl16(Bh + boff + k0 + 64 * 512, lw + 10240);
    gl16(Bl + boff + k0,            lw + 12288);
    gl16(Bl + boff + k0 + 64 * 512, lw + 14336);
    __syncthreads();

    bf16x8 aH[4], aL[4], bH[4], bL[4];
#pragma unroll
    for (int mi = 0; mi < 4; ++mi) {
      aH[mi] = *(const bf16x8*)(sm +        (arow + mi * 16) * 32 + kf);
      aL[mi] = *(const bf16x8*)(sm + 4096 + (arow + mi * 16) * 32 + kf);
    }
#pragma unroll
    for (int ni = 0; ni < 4; ++ni) {
      bH[ni] = *(const bf16x8*)(sm + 8192  + (brow + ni * 16) * 32 + kf);
      bL[ni] = *(const bf16x8*)(sm + 12288 + (brow + ni * 16) * 32 + kf);
    }
#pragma unroll
    for (int mi = 0; mi < 4; ++mi)
#pragma unroll
      for (int ni = 0; ni < 4; ++ni) {
        acc[mi][ni] = __builtin_amdgcn_mfma_f32_16x16x32_bf16(aH[mi], bH[ni], acc[mi][ni], 0, 0, 0);
        acc[mi][ni] = __builtin_amdgcn_mfma_f32_16x16x32_bf16(aH[mi], bL[ni], acc[mi][ni], 0, 0, 0);
        acc[mi][ni] = __builtin_amdgcn_mfma_f32_16x16x32_bf16(aL[mi], bH[ni], acc[mi][ni], 0, 0, 0);
      }
  }

  const int erow0 = m0 + ((wv >> 1) << 6) + ((lane >> 4) << 2);
  const int ecol0 = n0 + ((wv & 1) << 6) + (lane & 15);
#pragma unroll
  for (int mi = 0; mi < 4; ++mi)
#pragma unroll
    for (int r = 0; r < 4; ++r) {
      int row = erow0 + mi * 16 + r;
      if (row < G_ROWS) {
#pragma unroll
        for (int ni = 0; ni < 4; ++ni)
          Sim[(size_t)row * T_DIM + ecol0 + ni * 16] = acc[mi][ni][r] * SIM_SCALE;
      }
    }
}

// ---------------- helpers ----------------
__device__ __forceinline__ float wave_max_f(float v) {
#pragma unroll
  for (int off = 32; off > 0; off >>= 1) v = fmaxf(v, __shfl_xor(v, off, 64));
  return v;
}
__device__ __forceinline__ int count_above(const u32* u, u32 tau) {
  int c = 0;
#pragma unroll
  for (int j = 0; j < 24; ++j) c += (u[j] > tau) ? 1 : 0;
#pragma unroll
  for (int off = 32; off > 0; off >>= 1) c += __shfl_xor(c, off, 64);
  return c;
}

// ---------------- per-row (1 wave/row): bisect-select candidates on masked sim,
// np-replica f32 re-sim ONLY at contested boundary, top-32 + renormalized write ----
__global__ __launch_bounds__(256) void topk_kernel(float* __restrict__ Sim, const int* __restrict__ mask,
                                                   const float* __restrict__ tg_dec,
                                                   const float* __restrict__ tf_base,
                                                   int* __restrict__ tIdx, float* __restrict__ tW)
{
  __shared__ float srow[4][T_DIM];   // 24 KB sparse-writeback staging
  __shared__ u32   cval[4][64];
  __shared__ int   cidxs[4][64];
  const int lane = threadIdx.x & 63;
  const int wv   = threadIdx.x >> 6;
  const int g    = blockIdx.x * 4 + wv;
  float* row = Sim + (size_t)g * T_DIM;
  const int* mrow = mask + (size_t)g * T_DIM;

  // --- load, mask, map to orderable u32 (masked-out -> 0, below all valid) ---
  u32 u[24];
#pragma unroll
  for (int j = 0; j < 24; ++j) {
    float v = row[j * 64 + lane];
    int mk = mrow[j * 64 + lane];
    u32 b = __float_as_uint(v);
    u32 o = (b & 0x80000000u) ? ~b : (b | 0x80000000u);
    u[j] = mk ? o : 0u;
  }

  // --- bisection threshold search: candidate count in [36, 64] ---
  u32 tau = 0u;
  int cnt = count_above(u, 0u);        // = valid count (~768)
  if (cnt > 64) {
    u32 lo = 0u, hi = 0xFFFFFFFFu;
    bool found = false;
    for (int it = 0; it < 32 && !found; ++it) {
      u32 mid = lo + ((hi - lo) >> 1);
      int c = count_above(u, mid);
      if (c > 64)      lo = mid;
      else if (c < 36) hi = mid;
      else { tau = mid; found = true; }
    }
    if (!found) tau = lo;              // pathological ties only; compaction clamps
  }

  // --- ballot-prefix compaction of candidates into LDS (idx-ascending order) ---
  int base = 0;
#pragma unroll
  for (int j = 0; j < 24; ++j) {
    bool pred = (u[j] > tau);
    u64 bm = __ballot(pred);
    int pos = base + (int)__popcll(bm & ((1ull << lane) - 1ull));
    if (pred && pos < 64) { cval[wv][pos] = u[j]; cidxs[wv][pos] = j * 64 + lane; }
    base += (int)__popcll(bm);
  }
  const int cnt_eff = (base < 64) ? base : 64;
  __syncthreads();

  u32 myu = 0u; int myidx = 0x7FFFFFFF; float myv = -INFINITY;
  if (lane < cnt_eff) {
    myu = cval[wv][lane]; myidx = cidxs[wv][lane];
    u32 b = (myu & 0x80000000u) ? (myu & 0x7FFFFFFFu) : ~myu;
    myv = __uint_as_float(b);
  }

  // --- rank by (screened value desc, idx asc) ---
  u64 key = ((u64)myu << 32) | (u64)(u32)(~(u32)myidx);
  int rank = 0;
  for (int c = 0; c < 64; ++c) {
    u64 kc = __shfl(key, c, 64);
    rank += (kc > key) ? 1 : 0;
  }

  // --- contested boundary? np-replica re-sim only for candidates within eps of 31/32 cut ---
  float v31 = wave_max_f((rank == 31) ? myv : -INFINITY);
  float v32 = wave_max_f((rank == 32) ? myv : -INFINITY);
  bool flag = (cnt_eff > TOPK) && (lane < cnt_eff) &&
              (myv >= v32 - BOUND_EPS) && (myv <= v31 + BOUND_EPS);
  if (__ballot(flag) != 0ull) {
    if (flag) {
      // bit-exact np replica: OpenBLAS sgemm sequential-K FMA chain, kc split 384|128,
      // then f32 division by f32(sqrt(512)). Requires strict FP (no fast-math).
      const float* arow_g = tg_dec + (size_t)g * D_DIM;
      const float* brow   = tf_base + (size_t)myidx * D_DIM;
      float s1 = 0.f, s2 = 0.f;
#pragma unroll 8
      for (int k = 0; k < 384; k += 4) {
        float4 av = *(const float4*)(arow_g + k);
        float4 bv = *(const float4*)(brow + k);
        s1 = fmaf(av.x, bv.x, s1); s1 = fmaf(av.y, bv.y, s1);
        s1 = fmaf(av.z, bv.z, s1); s1 = fmaf(av.w, bv.w, s1);
      }
#pragma unroll 8
      for (int k = 384; k < 512; k += 4) {
        float4 av = *(const float4*)(arow_g + k);
        float4 bv = *(const float4*)(brow + k);
        s2 = fmaf(av.x, bv.x, s2); s2 = fmaf(av.y, bv.y, s2);
        s2 = fmaf(av.z, bv.z, s2); s2 = fmaf(av.w, bv.w, s2);
      }
      myv = (s1 + s2) / SQRT_D;
    }
    // re-rank with refined values (non-flagged keep screened; cross-eps order can't flip)
    u32 b2 = __float_as_uint(myv);
    u32 o2 = (b2 & 0x80000000u) ? ~b2 : (b2 | 0x80000000u);
    if (lane >= cnt_eff) o2 = 0u;
    key = ((u64)o2 << 32) | (u64)(u32)(~(u32)myidx);
    rank = 0;
    for (int c = 0; c < 64; ++c) {
      u64 kc = __shfl(key, c, 64);
      rank += (kc > key) ? 1 : 0;
    }
  }

  // --- weights (m-shift cancels exactly in ratio; 1e-8*Z term dropped: <=1.5e-5 abs) ---
  const bool selme = (lane < cnt_eff) && (rank < TOPK);
  float mx = wave_max_f(selme ? myv : -INFINITY);
  float e = selme ? __expf(myv - mx) : 0.f;
  float E = e;
#pragma unroll
  for (int off = 32; off > 0; off >>= 1) E += __shfl_xor(E, off, 64);
  float rden = (E > 0.f) ? (1.f / E) : 0.f;
  float w = e * rden;

  // --- sparse row write via LDS (zero -> scatter -> dense writeback) ---
#pragma unroll
  for (int j = 0; j < 24; ++j) srow[wv][j * 64 + lane] = 0.f;
  __syncthreads();
  if (selme) srow[wv][myidx] = w;
  __syncthreads();
#pragma unroll
  for (int j = 0; j < 24; ++j) row[j * 64 + lane] = srow[wv][j * 64 + lane];

  if (cnt_eff < TOPK && lane >= cnt_eff && lane < TOPK) {   // defensive (never for this input)
    tIdx[(size_t)g * TOPK + lane] = 0; tW[(size_t)g * TOPK + lane] = 0.f;
  }
  if (selme) {
    tIdx[(size_t)g * TOPK + rank] = myidx;
    tW[(size_t)g * TOPK + rank]   = w;
  }
}

// ---------------- out0[b,g] = scale * sum_k w[g,k] * tfT[idx[g,k], b] ----------------
__global__ __launch_bounds__(256) void combine_kernel(const float* __restrict__ tfT, const int* __restrict__ tIdx,
                                                      const float* __restrict__ tW, const float* __restrict__ scalep,
                                                      float* __restrict__ out0)
{
  __shared__ int   sIdx[16 * 32];
  __shared__ float sW[16 * 32];
  const int tid = threadIdx.x;
  const int g0 = blockIdx.x * 16;
  for (int i = tid; i < 512; i += 256) {
    sIdx[i] = tIdx[(size_t)g0 * 32 + i];
    sW[i]   = tW[(size_t)g0 * 32 + i];
  }
  __syncthreads();
  const float scale = scalep[0];
  float acc[16];
#pragma unroll
  for (int gi = 0; gi < 16; ++gi) acc[gi] = 0.f;
#pragma unroll 4
  for (int gi = 0; gi < 16; ++gi) {
    float a = 0.f;
#pragma unroll
    for (int k = 0; k < 32; ++k) {
      float w = sW[gi * 32 + k];
      int t   = sIdx[gi * 32 + k];
      a += w * tfT[(size_t)t * B_DIM + tid];
    }
    acc[gi] = a;
  }
  float* dst = out0 + (size_t)tid * G_ROWS + g0;
#pragma unroll
  for (int q = 0; q < 4; ++q) {
    float4 o = make_float4(scale * acc[4*q], scale * acc[4*q+1], scale * acc[4*q+2], scale * acc[4*q+3]);
    *(float4*)(dst + 4 * q) = o;
  }
}

extern "C" void kernel_launch(void* const* d_in, const int* in_sizes, int n_in,
                              void* d_out, int out_size, void* d_ws, size_t ws_size,
                              hipStream_t stream)
{
  const float* tg_dec     = (const float*)d_in[0];
  const float* tf_base    = (const float*)d_in[1];
  const float* tf_expr    = (const float*)d_in[2];
  const int*   motif_mask = (const int*)d_in[3];
  const float* scale      = (const float*)d_in[4];

  float* out0 = (float*)d_out;                           // [B, G]
  float* attn = out0 + (size_t)B_DIM * G_ROWS;           // [G, T] — also Sim scratch

  char* ws = (char*)d_ws;
  u16*   Ah  = (u16*)(ws);                               // G_PAD*512 bf16
  u16*   Al  = (u16*)(ws + 20578304);
  u16*   Bh  = (u16*)(ws + 41156608);                    // 1536*512 bf16
  u16*   Bl  = (u16*)(ws + 42729472);
  float* tfT = (float*)(ws + 44302336);                  // [T, B] f32
  int*   tIdx = (int*)(ws + 45875200);                   // [G, 32]
  float* tW   = (float*)(ws + 48435200);                 // [G, 32]

  conv_split<<<10048, 256, 0, stream>>>(tg_dec, Ah, Al, G_ROWS);
  conv_split<<<768,   256, 0, stream>>>(tf_base, Bh, Bl, T_DIM);
  transpose_tf<<<dim3(48, 8), dim3(32, 8), 0, stream>>>(tf_expr, tfT);
  gemm_split<<<dim3(12, 157), 256, 0, stream>>>(Ah, Al, Bh, Bl, attn);
  topk_kernel<<<5000, 256, 0, stream>>>(attn, motif_mask, tg_dec, tf_base, tIdx, tW);
  combine_kernel<<<1250, 256, 0, stream>>>(tfT, tIdx, tW, scale, out0);
}